// Round 4
// baseline (292.842 us; speedup 1.0000x reference)
//
#include <hip/hip_runtime.h>

typedef unsigned int u32;
typedef unsigned long long u64;

#define T_ 4
#define B_ 32
#define E_ 1024
#define H_ 16
#define HD_ 64
#define CACHE_ 4096
#define S_ 4100
#define SPLIT_ 2
#define NEGINF (-__builtin_inff())

// ---------------- mask dtype detection: 1 = bool bytes, 0 = int32 ----------------
__global__ void detect_mask(const unsigned char* __restrict__ m, int* __restrict__ flag) {
    __shared__ int cnt_s;
    if (threadIdx.x == 0) cnt_s = 0;
    __syncthreads();
    int cnt = 0;
    for (int i = threadIdx.x; i < 8192; i += 256) cnt += (m[i] != 0) ? 1 : 0;
#pragma unroll
    for (int off = 32; off; off >>= 1) cnt += __shfl_xor(cnt, off);
    if ((threadIdx.x & 63) == 0) atomicAdd(&cnt_s, cnt);
    __syncthreads();
    if (threadIdx.x == 0) *flag = (cnt_s > 2048) ? 1 : 0;
}

// ---------------- per-batch compaction of unmasked cache positions ----------------
__global__ __launch_bounds__(256) void compact_kernel(
    const unsigned char* __restrict__ mask8, const int* __restrict__ flag,
    int* __restrict__ cidx, int* __restrict__ ccnt)
{
    const int b = blockIdx.x;
    const int tid = threadIdx.x;
    const int w = tid >> 6, l = tid & 63;
    const int mode = *flag;
    const int* mask32 = (const int*)mask8;
    __shared__ int wcnt[4];
    __shared__ int base_s;
    if (tid == 0) base_s = 0;
    __syncthreads();
    for (int s0 = 0; s0 < CACHE_; s0 += 256) {
        int s = s0 + tid;
        bool ok = mode ? (mask8[(size_t)b * S_ + s] == 0) : (mask32[(size_t)b * S_ + s] == 0);
        u64 bal = __ballot(ok);
        int pre = (int)__popcll(bal & ((1ull << l) - 1));
        if (l == 0) wcnt[w] = (int)__popcll(bal);
        __syncthreads();
        int off = base_s;
#pragma unroll
        for (int i = 0; i < 4; i++) if (i < w) off += wcnt[i];
        if (ok) cidx[b * CACHE_ + off + pre] = s;
        __syncthreads();
        if (tid == 0) base_s += wcnt[0] + wcnt[1] + wcnt[2] + wcnt[3];
        __syncthreads();
    }
    if (tid == 0) ccnt[b] = base_s;
}

// ---------------- fused QKV projection (f32) ----------------
__global__ __launch_bounds__(256) void proj_kernel(
    const float* __restrict__ q,
    const float* __restrict__ Wq, const float* __restrict__ bq,
    const float* __restrict__ Wk, const float* __restrict__ bk,
    const float* __restrict__ Wv, const float* __restrict__ bv,
    float* __restrict__ qs, float* __restrict__ kn, float* __restrict__ vn)
{
    __shared__ float A_l[64][33];
    __shared__ float W_l[16][33];
    const int bx = blockIdx.x;
    const int mat = bx >> 7;
    const int rem = bx & 127;
    const int ct = rem >> 1, rt = rem & 1;
    const int c0 = ct * 16, r0 = rt * 64;
    const float* W    = (mat == 0) ? Wq : (mat == 1) ? Wk : Wv;
    const float* bias = (mat == 0) ? bq : (mat == 1) ? bk : bv;
    const int tid = threadIdx.x;
    const int row = tid & 63, cg = tid >> 6;
    float acc[4] = {0.f, 0.f, 0.f, 0.f};

    for (int k0 = 0; k0 < 1024; k0 += 32) {
        __syncthreads();
        for (int j = tid; j < 512; j += 256) {
            int ar = j >> 3, kk = (j & 7) * 4;
            float4 v = *(const float4*)(q + (size_t)(r0 + ar) * 1024 + k0 + kk);
            A_l[ar][kk] = v.x; A_l[ar][kk + 1] = v.y;
            A_l[ar][kk + 2] = v.z; A_l[ar][kk + 3] = v.w;
        }
        if (tid < 128) {
            int wr = tid >> 3, kk = (tid & 7) * 4;
            float4 v = *(const float4*)(W + (size_t)(c0 + wr) * 1024 + k0 + kk);
            W_l[wr][kk] = v.x; W_l[wr][kk + 1] = v.y;
            W_l[wr][kk + 2] = v.z; W_l[wr][kk + 3] = v.w;
        }
        __syncthreads();
#pragma unroll
        for (int kk = 0; kk < 32; kk++) {
            float a = A_l[row][kk];
#pragma unroll
            for (int j = 0; j < 4; j++) acc[j] += a * W_l[cg * 4 + j][kk];
        }
    }
    const int r = r0 + row;
    const int t = r >> 5, b = r & 31;
#pragma unroll
    for (int j = 0; j < 4; j++) {
        int c = c0 + cg * 4 + j;
        float val = acc[j] + bias[c];
        int h = c >> 6, d = c & 63;
        size_t oidx = ((size_t)((b * H_ + h) * T_ + t)) * HD_ + d;
        if (mat == 0) qs[oidx] = val * 0.125f;
        else if (mat == 1) kn[oidx] = val;
        else vn[oidx] = val;
    }
}

// ---------------- attention: barrier-free register-resident flash decode ----------------
// Grid: 512 * SPLIT_ blocks. Block (bh, split) processes compacted positions
// [lo, hi). Each wave owns disjoint rows; lane l = (group r4 = l>>2, quarter
// q4 = l&3) holds 16 floats of one K row and one V row in registers.
// Per-wave online softmax; partials (m, l, acc[4][64]) written for merge.
__global__ __launch_bounds__(256) void attn_kernel(
    const float* __restrict__ kcache, const float* __restrict__ vcache,
    const float* __restrict__ qs,
    const int* __restrict__ cidx, const int* __restrict__ ccnt,
    float* __restrict__ part_ml, float* __restrict__ part_acc)
{
    const int bid = blockIdx.x;
    const int bh = bid >> 1, split = bid & 1;
    const int b = bh >> 4;
    const int tid = threadIdx.x;
    const int w = tid >> 6, l = tid & 63;
    const int q4 = l & 3, r4 = l >> 2;

    __shared__ float q_l[256];
    __shared__ int cidx_l[2048];

    const int cnt = ccnt[b];
    const int half = (cnt + 1) >> 1;
    const int lo = split * half;
    const int hi = min(cnt, lo + half);
    const int n = hi - lo;

    q_l[tid] = qs[bh * 256 + tid];
    for (int i = tid; i < n; i += 256) cidx_l[i] = cidx[b * CACHE_ + lo + i];
    __syncthreads();

    float acc[4][16];
#pragma unroll
    for (int t = 0; t < 4; t++)
#pragma unroll
        for (int j = 0; j < 16; j++) acc[t][j] = 0.f;
    float m[4] = {NEGINF, NEGINF, NEGINF, NEGINF};
    float L[4] = {0.f, 0.f, 0.f, 0.f};

    // lane's 16 floats of a row: d = x*16 + q4*4 + {0..3}, x = 0..3
    // -> each dwordx4 instruction covers one full 64B line per 4-lane group.
    const float* kbase = kcache + (size_t)bh * (CACHE_ * HD_) + q4 * 4;
    const float* vbase = vcache + (size_t)bh * (CACHE_ * HD_) + q4 * 4;

    const int nch = (n + 63) >> 6;
    float4 ka[4], va[4];

    if (nch > 0) {
        int p = w * 16 + r4;
        int idx = cidx_l[min(p, n - 1)];
#pragma unroll
        for (int x = 0; x < 4; x++) ka[x] = *(const float4*)(kbase + (size_t)idx * HD_ + x * 16);
#pragma unroll
        for (int x = 0; x < 4; x++) va[x] = *(const float4*)(vbase + (size_t)idx * HD_ + x * 16);
    }

    for (int c = 0; c < nch; c++) {
        // ---- score partials from K registers ----
        float part[4] = {0.f, 0.f, 0.f, 0.f};
#pragma unroll
        for (int x = 0; x < 4; x++) {
            float4 kf = ka[x];
#pragma unroll
            for (int t = 0; t < 4; t++) {
                float4 qf = *(const float4*)&q_l[t * 64 + x * 16 + q4 * 4];
                part[t] += qf.x * kf.x + qf.y * kf.y + qf.z * kf.z + qf.w * kf.w;
            }
        }
        // ---- prefetch next-chunk K (ka registers now dead) ----
        if (c + 1 < nch) {
            int p = (c + 1) * 64 + w * 16 + r4;
            int idx = cidx_l[min(p, n - 1)];
#pragma unroll
            for (int x = 0; x < 4; x++) ka[x] = *(const float4*)(kbase + (size_t)idx * HD_ + x * 16);
        }
        const bool valid = (c * 64 + w * 16 + r4) < n;
        float pe[4];
#pragma unroll
        for (int t = 0; t < 4; t++) {
            float s = part[t];
            s += __shfl_xor(s, 1);
            s += __shfl_xor(s, 2);          // full dot, equal within 4-lane group
            s = valid ? s : NEGINF;
            float mx = s;
            mx = fmaxf(mx, __shfl_xor(mx, 4));
            mx = fmaxf(mx, __shfl_xor(mx, 8));
            mx = fmaxf(mx, __shfl_xor(mx, 16));
            mx = fmaxf(mx, __shfl_xor(mx, 32));   // wave max over 16 rows
            if (mx > m[t] + 8.f) {          // defer-max (T13): rare rescale
                float fac = __expf(m[t] - mx);
                L[t] *= fac;
#pragma unroll
                for (int j = 0; j < 16; j++) acc[t][j] *= fac;
                m[t] = mx;
            }
            float e = (s == NEGINF) ? 0.f : __expf(s - m[t]);
            float rs = e;
            rs += __shfl_xor(rs, 4);
            rs += __shfl_xor(rs, 8);
            rs += __shfl_xor(rs, 16);
            rs += __shfl_xor(rs, 32);       // sums 16 distinct rows exactly once
            L[t] += rs;
            pe[t] = e;
        }
        // ---- PV from V registers ----
#pragma unroll
        for (int t = 0; t < 4; t++) {
#pragma unroll
            for (int x = 0; x < 4; x++) {
                acc[t][x * 4 + 0] += pe[t] * va[x].x;
                acc[t][x * 4 + 1] += pe[t] * va[x].y;
                acc[t][x * 4 + 2] += pe[t] * va[x].z;
                acc[t][x * 4 + 3] += pe[t] * va[x].w;
            }
        }
        // ---- prefetch next-chunk V (va registers now dead) ----
        if (c + 1 < nch) {
            int p = (c + 1) * 64 + w * 16 + r4;
            int idx = cidx_l[min(p, n - 1)];
#pragma unroll
            for (int x = 0; x < 4; x++) va[x] = *(const float4*)(vbase + (size_t)idx * HD_ + x * 16);
        }
    }

    // reduce acc across the 16 row-groups of the wave
#pragma unroll
    for (int t = 0; t < 4; t++)
#pragma unroll
        for (int j = 0; j < 16; j++) {
            float v = acc[t][j];
            v += __shfl_xor(v, 4);
            v += __shfl_xor(v, 8);
            v += __shfl_xor(v, 16);
            v += __shfl_xor(v, 32);
            acc[t][j] = v;
        }

    const int pidx = bid * 4 + w;           // [0, 4096)
    if (l < 4) {                            // lanes 0..3: quarters 0..3
#pragma unroll
        for (int t = 0; t < 4; t++)
#pragma unroll
            for (int x = 0; x < 4; x++) {
                float4 o = make_float4(acc[t][x * 4], acc[t][x * 4 + 1],
                                       acc[t][x * 4 + 2], acc[t][x * 4 + 3]);
                *(float4*)&part_acc[((size_t)pidx * 4 + t) * HD_ + x * 16 + l * 4] = o;
            }
    }
    if (l == 0) {
#pragma unroll
        for (int t = 0; t < 4; t++) {
            part_ml[pidx * 8 + t * 2 + 0] = m[t];
            part_ml[pidx * 8 + t * 2 + 1] = L[t];
        }
    }
}

// ---------------- merge partials + new tokens + normalize ----------------
__global__ __launch_bounds__(256) void merge_kernel(
    const float* __restrict__ part_ml, const float* __restrict__ part_acc,
    const float* __restrict__ qs, const float* __restrict__ kn,
    const float* __restrict__ vn,
    const unsigned char* __restrict__ mask8, const int* __restrict__ flag,
    float* __restrict__ attn_out)
{
    const int bh = blockIdx.x;
    const int b = bh >> 4, h = bh & 15;
    const int tid = threadIdx.x;
    const int t = tid >> 6, d = tid & 63;
    const int mode = *flag;
    const int* mask32 = (const int*)mask8;

    float M = NEGINF;
#pragma unroll
    for (int i = 0; i < 8; i++) M = fmaxf(M, part_ml[(bh * 8 + i) * 8 + t * 2]);
    float acc = 0.f, L = 0.f;
#pragma unroll
    for (int i = 0; i < 8; i++) {
        float mi = part_ml[(bh * 8 + i) * 8 + t * 2];
        float li = part_ml[(bh * 8 + i) * 8 + t * 2 + 1];
        if (mi > NEGINF) {
            float wgt = __expf(mi - M);
            L += li * wgt;
            acc += part_acc[((size_t)(bh * 8 + i) * 4 + t) * HD_ + d] * wgt;
        }
    }

    // new-token keys (positions CACHE_..CACHE_+3)
    float qv = qs[bh * 256 + t * 64 + d];
    float sn[4];
#pragma unroll
    for (int i = 0; i < 4; i++) {
        size_t mi_ = (size_t)b * S_ + CACHE_ + i;
        bool masked = mode ? (mask8[mi_] != 0) : (mask32[mi_] != 0);
        float prod = qv * kn[bh * 256 + i * 64 + d];
        prod += __shfl_xor(prod, 1);
        prod += __shfl_xor(prod, 2);
        prod += __shfl_xor(prod, 4);
        prod += __shfl_xor(prod, 8);
        prod += __shfl_xor(prod, 16);
        prod += __shfl_xor(prod, 32);
        sn[i] = masked ? NEGINF : prod;
    }
    float M2 = M;
#pragma unroll
    for (int i = 0; i < 4; i++) M2 = fmaxf(M2, sn[i]);
    if (M2 > NEGINF) {
        if (M > NEGINF) {
            float wo = __expf(M - M2);
            acc *= wo; L *= wo;
        }
#pragma unroll
        for (int i = 0; i < 4; i++) {
            if (sn[i] > NEGINF) {
                float e = __expf(sn[i] - M2);
                L += e;
                acc += e * vn[bh * 256 + i * 64 + d];
            }
        }
    }
    float o = (L > 0.f) ? acc / L : 0.f;
    attn_out[(size_t)(t * B_ + b) * E_ + h * HD_ + d] = o;
}

// ---------------- output projection (f32 -> f32) ----------------
__global__ __launch_bounds__(256) void oproj_kernel(
    const float* __restrict__ A,
    const float* __restrict__ W, const float* __restrict__ bias,
    float* __restrict__ out)
{
    __shared__ float A_l[64][33];
    __shared__ float W_l[16][33];
    const int bx = blockIdx.x;
    const int ct = bx >> 1, rt = bx & 1;
    const int c0 = ct * 16, r0 = rt * 64;
    const int tid = threadIdx.x;
    const int row = tid & 63, cg = tid >> 6;
    float acc[4] = {0.f, 0.f, 0.f, 0.f};

    for (int k0 = 0; k0 < 1024; k0 += 32) {
        __syncthreads();
        for (int j = tid; j < 512; j += 256) {
            int ar = j >> 3, kk = (j & 7) * 4;
            float4 v = *(const float4*)(A + (size_t)(r0 + ar) * 1024 + k0 + kk);
            A_l[ar][kk] = v.x; A_l[ar][kk + 1] = v.y;
            A_l[ar][kk + 2] = v.z; A_l[ar][kk + 3] = v.w;
        }
        if (tid < 128) {
            int wr = tid >> 3, kk = (tid & 7) * 4;
            float4 v = *(const float4*)(W + (size_t)(c0 + wr) * 1024 + k0 + kk);
            W_l[wr][kk] = v.x; W_l[wr][kk + 1] = v.y;
            W_l[wr][kk + 2] = v.z; W_l[wr][kk + 3] = v.w;
        }
        __syncthreads();
#pragma unroll
        for (int kk = 0; kk < 32; kk++) {
            float a = A_l[row][kk];
#pragma unroll
            for (int j = 0; j < 4; j++) acc[j] += a * W_l[cg * 4 + j][kk];
        }
    }
    const int r = r0 + row;
#pragma unroll
    for (int j = 0; j < 4; j++) {
        int c = c0 + cg * 4 + j;
        out[(size_t)r * 1024 + c] = acc[j] + bias[c];
    }
}

extern "C" void kernel_launch(void* const* d_in, const int* in_sizes, int n_in,
                              void* d_out, int out_size, void* d_ws, size_t ws_size,
                              hipStream_t stream) {
    const float* query = (const float*)d_in[0];
    // d_in[1] = key: unused by the reference (k_new/v_new project from query)
    const unsigned char* mask = (const unsigned char*)d_in[2];
    const float* kcache = (const float*)d_in[3];
    const float* vcache = (const float*)d_in[4];
    const float* Wq = (const float*)d_in[5];
    const float* bq = (const float*)d_in[6];
    const float* Wk = (const float*)d_in[7];
    const float* bk = (const float*)d_in[8];
    const float* Wv = (const float*)d_in[9];
    const float* bv = (const float*)d_in[10];
    const float* Wo = (const float*)d_in[11];
    const float* bo = (const float*)d_in[12];

    char* ws = (char*)d_ws;
    float* qs   = (float*)(ws);                       // 512 KB
    float* kn   = (float*)(ws + ( 512ull << 10));     // 512 KB
    float* vn   = (float*)(ws + (1024ull << 10));     // 512 KB
    float* att  = (float*)(ws + (1536ull << 10));     // 512 KB
    int*   flag = (int*)  (ws + (2048ull << 10));     // 4 B
    int*   cidx = (int*)  (ws + (2049ull << 10));     // 512 KB
    int*   ccnt = (int*)  (ws + (2562ull << 10));     // 128 B
    float* pml  = (float*)(ws + (2563ull << 10));     // 128 KB
    float* pacc = (float*)(ws + (3072ull << 10));     // 4 MB

    detect_mask<<<1, 256, 0, stream>>>(mask, flag);
    compact_kernel<<<B_, 256, 0, stream>>>(mask, flag, cidx, ccnt);
    proj_kernel<<<384, 256, 0, stream>>>(query, Wq, bq, Wk, bk, Wv, bv, qs, kn, vn);
    attn_kernel<<<512 * SPLIT_, 256, 0, stream>>>(kcache, vcache, qs, cidx, ccnt, pml, pacc);
    merge_kernel<<<512, 256, 0, stream>>>(pml, pacc, qs, kn, vn, mask, flag, att);
    oproj_kernel<<<128, 256, 0, stream>>>(att, Wo, bo, (float*)d_out);
}

// Round 5
// 291.668 us; speedup vs baseline: 1.0040x; 1.0040x over previous
//
#include <hip/hip_runtime.h>

typedef unsigned int u32;
typedef unsigned long long u64;

#define T_ 4
#define B_ 32
#define E_ 1024
#define H_ 16
#define HD_ 64
#define CACHE_ 4096
#define S_ 4100
#define SPLIT_ 2
#define NEGINF (-__builtin_inff())

// ---------------- mask dtype detection: 1 = bool bytes, 0 = int32 ----------------
__global__ void detect_mask(const unsigned char* __restrict__ m, int* __restrict__ flag) {
    __shared__ int cnt_s;
    if (threadIdx.x == 0) cnt_s = 0;
    __syncthreads();
    int cnt = 0;
    for (int i = threadIdx.x; i < 8192; i += 256) cnt += (m[i] != 0) ? 1 : 0;
#pragma unroll
    for (int off = 32; off; off >>= 1) cnt += __shfl_xor(cnt, off);
    if ((threadIdx.x & 63) == 0) atomicAdd(&cnt_s, cnt);
    __syncthreads();
    if (threadIdx.x == 0) *flag = (cnt_s > 2048) ? 1 : 0;
}

// ---------------- per-batch compaction of unmasked cache positions ----------------
__global__ __launch_bounds__(256) void compact_kernel(
    const unsigned char* __restrict__ mask8, const int* __restrict__ flag,
    int* __restrict__ cidx, int* __restrict__ ccnt)
{
    const int b = blockIdx.x;
    const int tid = threadIdx.x;
    const int w = tid >> 6, l = tid & 63;
    const int mode = *flag;
    const int* mask32 = (const int*)mask8;
    __shared__ int wcnt[4];
    __shared__ int base_s;
    if (tid == 0) base_s = 0;
    __syncthreads();
    for (int s0 = 0; s0 < CACHE_; s0 += 256) {
        int s = s0 + tid;
        bool ok = mode ? (mask8[(size_t)b * S_ + s] == 0) : (mask32[(size_t)b * S_ + s] == 0);
        u64 bal = __ballot(ok);
        int pre = (int)__popcll(bal & ((1ull << l) - 1));
        if (l == 0) wcnt[w] = (int)__popcll(bal);
        __syncthreads();
        int off = base_s;
#pragma unroll
        for (int i = 0; i < 4; i++) if (i < w) off += wcnt[i];
        if (ok) cidx[b * CACHE_ + off + pre] = s;
        __syncthreads();
        if (tid == 0) base_s += wcnt[0] + wcnt[1] + wcnt[2] + wcnt[3];
        __syncthreads();
    }
    if (tid == 0) ccnt[b] = base_s;
}

// ---------------- fused QKV projection (f32) ----------------
__global__ __launch_bounds__(256) void proj_kernel(
    const float* __restrict__ q,
    const float* __restrict__ Wq, const float* __restrict__ bq,
    const float* __restrict__ Wk, const float* __restrict__ bk,
    const float* __restrict__ Wv, const float* __restrict__ bv,
    float* __restrict__ qs, float* __restrict__ kn, float* __restrict__ vn)
{
    __shared__ float A_l[64][33];
    __shared__ float W_l[16][33];
    const int bx = blockIdx.x;
    const int mat = bx >> 7;
    const int rem = bx & 127;
    const int ct = rem >> 1, rt = rem & 1;
    const int c0 = ct * 16, r0 = rt * 64;
    const float* W    = (mat == 0) ? Wq : (mat == 1) ? Wk : Wv;
    const float* bias = (mat == 0) ? bq : (mat == 1) ? bk : bv;
    const int tid = threadIdx.x;
    const int row = tid & 63, cg = tid >> 6;
    float acc[4] = {0.f, 0.f, 0.f, 0.f};

    for (int k0 = 0; k0 < 1024; k0 += 32) {
        __syncthreads();
        for (int j = tid; j < 512; j += 256) {
            int ar = j >> 3, kk = (j & 7) * 4;
            float4 v = *(const float4*)(q + (size_t)(r0 + ar) * 1024 + k0 + kk);
            A_l[ar][kk] = v.x; A_l[ar][kk + 1] = v.y;
            A_l[ar][kk + 2] = v.z; A_l[ar][kk + 3] = v.w;
        }
        if (tid < 128) {
            int wr = tid >> 3, kk = (tid & 7) * 4;
            float4 v = *(const float4*)(W + (size_t)(c0 + wr) * 1024 + k0 + kk);
            W_l[wr][kk] = v.x; W_l[wr][kk + 1] = v.y;
            W_l[wr][kk + 2] = v.z; W_l[wr][kk + 3] = v.w;
        }
        __syncthreads();
#pragma unroll
        for (int kk = 0; kk < 32; kk++) {
            float a = A_l[row][kk];
#pragma unroll
            for (int j = 0; j < 4; j++) acc[j] += a * W_l[cg * 4 + j][kk];
        }
    }
    const int r = r0 + row;
    const int t = r >> 5, b = r & 31;
#pragma unroll
    for (int j = 0; j < 4; j++) {
        int c = c0 + cg * 4 + j;
        float val = acc[j] + bias[c];
        int h = c >> 6, d = c & 63;
        size_t oidx = ((size_t)((b * H_ + h) * T_ + t)) * HD_ + d;
        if (mat == 0) qs[oidx] = val * 0.125f;
        else if (mat == 1) kn[oidx] = val;
        else vn[oidx] = val;
    }
}

// ---------------- attention: barrier-free register-resident flash decode ----------------
// Grid: 512 * SPLIT_ blocks. Block (bh, split) processes compacted positions
// [lo, hi). Each wave owns disjoint rows; lane l = (group r4 = l>>2, quarter
// q4 = l&3) holds 16 floats of one K row and one V row in registers.
// Per-wave online softmax; partials (m, l, acc[4][64]) written for merge.
__global__ __launch_bounds__(256) void attn_kernel(
    const float* __restrict__ kcache, const float* __restrict__ vcache,
    const float* __restrict__ qs,
    const int* __restrict__ cidx, const int* __restrict__ ccnt,
    float* __restrict__ part_ml, float* __restrict__ part_acc)
{
    const int bid = blockIdx.x;
    const int bh = bid >> 1, split = bid & 1;
    const int b = bh >> 4;
    const int tid = threadIdx.x;
    const int w = tid >> 6, l = tid & 63;
    const int q4 = l & 3, r4 = l >> 2;

    __shared__ float q_l[256];
    __shared__ int cidx_l[2048];

    const int cnt = ccnt[b];
    const int half = (cnt + 1) >> 1;
    const int lo = split * half;
    const int hi = min(cnt, lo + half);
    const int n = hi - lo;

    q_l[tid] = qs[bh * 256 + tid];
    for (int i = tid; i < n; i += 256) cidx_l[i] = cidx[b * CACHE_ + lo + i];
    __syncthreads();

    float acc[4][16];
#pragma unroll
    for (int t = 0; t < 4; t++)
#pragma unroll
        for (int j = 0; j < 16; j++) acc[t][j] = 0.f;
    float m[4] = {NEGINF, NEGINF, NEGINF, NEGINF};
    float L[4] = {0.f, 0.f, 0.f, 0.f};

    // lane's 16 floats of a row: d = x*16 + q4*4 + {0..3}, x = 0..3
    // -> each dwordx4 instruction covers one full 64B line per 4-lane group.
    const float* kbase = kcache + (size_t)bh * (CACHE_ * HD_) + q4 * 4;
    const float* vbase = vcache + (size_t)bh * (CACHE_ * HD_) + q4 * 4;

    const int nch = (n + 63) >> 6;
    float4 ka[4], va[4];

    if (nch > 0) {
        int p = w * 16 + r4;
        int idx = cidx_l[min(p, n - 1)];
#pragma unroll
        for (int x = 0; x < 4; x++) ka[x] = *(const float4*)(kbase + (size_t)idx * HD_ + x * 16);
#pragma unroll
        for (int x = 0; x < 4; x++) va[x] = *(const float4*)(vbase + (size_t)idx * HD_ + x * 16);
    }

    for (int c = 0; c < nch; c++) {
        // ---- score partials from K registers ----
        float part[4] = {0.f, 0.f, 0.f, 0.f};
#pragma unroll
        for (int x = 0; x < 4; x++) {
            float4 kf = ka[x];
#pragma unroll
            for (int t = 0; t < 4; t++) {
                float4 qf = *(const float4*)&q_l[t * 64 + x * 16 + q4 * 4];
                part[t] += qf.x * kf.x + qf.y * kf.y + qf.z * kf.z + qf.w * kf.w;
            }
        }
        // ---- prefetch next-chunk K (ka registers now dead) ----
        if (c + 1 < nch) {
            int p = (c + 1) * 64 + w * 16 + r4;
            int idx = cidx_l[min(p, n - 1)];
#pragma unroll
            for (int x = 0; x < 4; x++) ka[x] = *(const float4*)(kbase + (size_t)idx * HD_ + x * 16);
        }
        const bool valid = (c * 64 + w * 16 + r4) < n;
        float pe[4];
#pragma unroll
        for (int t = 0; t < 4; t++) {
            float s = part[t];
            s += __shfl_xor(s, 1);
            s += __shfl_xor(s, 2);          // full dot, equal within 4-lane group
            s = valid ? s : NEGINF;
            float mx = s;
            mx = fmaxf(mx, __shfl_xor(mx, 4));
            mx = fmaxf(mx, __shfl_xor(mx, 8));
            mx = fmaxf(mx, __shfl_xor(mx, 16));
            mx = fmaxf(mx, __shfl_xor(mx, 32));   // wave max over 16 rows
            if (mx > m[t] + 8.f) {          // defer-max (T13): rare rescale
                float fac = __expf(m[t] - mx);
                L[t] *= fac;
#pragma unroll
                for (int j = 0; j < 16; j++) acc[t][j] *= fac;
                m[t] = mx;
            }
            float e = (s == NEGINF) ? 0.f : __expf(s - m[t]);
            float rs = e;
            rs += __shfl_xor(rs, 4);
            rs += __shfl_xor(rs, 8);
            rs += __shfl_xor(rs, 16);
            rs += __shfl_xor(rs, 32);       // sums 16 distinct rows exactly once
            L[t] += rs;
            pe[t] = e;
        }
        // ---- PV from V registers ----
#pragma unroll
        for (int t = 0; t < 4; t++) {
#pragma unroll
            for (int x = 0; x < 4; x++) {
                acc[t][x * 4 + 0] += pe[t] * va[x].x;
                acc[t][x * 4 + 1] += pe[t] * va[x].y;
                acc[t][x * 4 + 2] += pe[t] * va[x].z;
                acc[t][x * 4 + 3] += pe[t] * va[x].w;
            }
        }
        // ---- prefetch next-chunk V (va registers now dead) ----
        if (c + 1 < nch) {
            int p = (c + 1) * 64 + w * 16 + r4;
            int idx = cidx_l[min(p, n - 1)];
#pragma unroll
            for (int x = 0; x < 4; x++) va[x] = *(const float4*)(vbase + (size_t)idx * HD_ + x * 16);
        }
    }

    // reduce acc across the 16 row-groups of the wave
#pragma unroll
    for (int t = 0; t < 4; t++)
#pragma unroll
        for (int j = 0; j < 16; j++) {
            float v = acc[t][j];
            v += __shfl_xor(v, 4);
            v += __shfl_xor(v, 8);
            v += __shfl_xor(v, 16);
            v += __shfl_xor(v, 32);
            acc[t][j] = v;
        }

    const int pidx = bid * 4 + w;           // [0, 4096)
    if (l < 4) {                            // lanes 0..3: quarters 0..3
#pragma unroll
        for (int t = 0; t < 4; t++)
#pragma unroll
            for (int x = 0; x < 4; x++) {
                float4 o = make_float4(acc[t][x * 4], acc[t][x * 4 + 1],
                                       acc[t][x * 4 + 2], acc[t][x * 4 + 3]);
                *(float4*)&part_acc[((size_t)pidx * 4 + t) * HD_ + x * 16 + l * 4] = o;
            }
    }
    if (l == 0) {
#pragma unroll
        for (int t = 0; t < 4; t++) {
            part_ml[pidx * 8 + t * 2 + 0] = m[t];
            part_ml[pidx * 8 + t * 2 + 1] = L[t];
        }
    }
}

// ---------------- merge partials + new tokens + normalize ----------------
__global__ __launch_bounds__(256) void merge_kernel(
    const float* __restrict__ part_ml, const float* __restrict__ part_acc,
    const float* __restrict__ qs, const float* __restrict__ kn,
    const float* __restrict__ vn,
    const unsigned char* __restrict__ mask8, const int* __restrict__ flag,
    float* __restrict__ attn_out)
{
    const int bh = blockIdx.x;
    const int b = bh >> 4, h = bh & 15;
    const int tid = threadIdx.x;
    const int t = tid >> 6, d = tid & 63;
    const int mode = *flag;
    const int* mask32 = (const int*)mask8;

    float M = NEGINF;
#pragma unroll
    for (int i = 0; i < 8; i++) M = fmaxf(M, part_ml[(bh * 8 + i) * 8 + t * 2]);
    float acc = 0.f, L = 0.f;
#pragma unroll
    for (int i = 0; i < 8; i++) {
        float mi = part_ml[(bh * 8 + i) * 8 + t * 2];
        float li = part_ml[(bh * 8 + i) * 8 + t * 2 + 1];
        if (mi > NEGINF) {
            float wgt = __expf(mi - M);
            L += li * wgt;
            acc += part_acc[((size_t)(bh * 8 + i) * 4 + t) * HD_ + d] * wgt;
        }
    }

    // new-token keys (positions CACHE_..CACHE_+3)
    float qv = qs[bh * 256 + t * 64 + d];
    float sn[4];
#pragma unroll
    for (int i = 0; i < 4; i++) {
        size_t mi_ = (size_t)b * S_ + CACHE_ + i;
        bool masked = mode ? (mask8[mi_] != 0) : (mask32[mi_] != 0);
        float prod = qv * kn[bh * 256 + i * 64 + d];
        prod += __shfl_xor(prod, 1);
        prod += __shfl_xor(prod, 2);
        prod += __shfl_xor(prod, 4);
        prod += __shfl_xor(prod, 8);
        prod += __shfl_xor(prod, 16);
        prod += __shfl_xor(prod, 32);
        sn[i] = masked ? NEGINF : prod;
    }
    float M2 = M;
#pragma unroll
    for (int i = 0; i < 4; i++) M2 = fmaxf(M2, sn[i]);
    if (M2 > NEGINF) {
        if (M > NEGINF) {
            float wo = __expf(M - M2);
            acc *= wo; L *= wo;
        }
#pragma unroll
        for (int i = 0; i < 4; i++) {
            if (sn[i] > NEGINF) {
                float e = __expf(sn[i] - M2);
                L += e;
                acc += e * vn[bh * 256 + i * 64 + d];
            }
        }
    }
    float o = (L > 0.f) ? acc / L : 0.f;
    attn_out[(size_t)(t * B_ + b) * E_ + h * HD_ + d] = o;
}

// ---------------- output projection (f32 -> f32) ----------------
__global__ __launch_bounds__(256) void oproj_kernel(
    const float* __restrict__ A,
    const float* __restrict__ W, const float* __restrict__ bias,
    float* __restrict__ out)
{
    __shared__ float A_l[64][33];
    __shared__ float W_l[16][33];
    const int bx = blockIdx.x;
    const int ct = bx >> 1, rt = bx & 1;
    const int c0 = ct * 16, r0 = rt * 64;
    const int tid = threadIdx.x;
    const int row = tid & 63, cg = tid >> 6;
    float acc[4] = {0.f, 0.f, 0.f, 0.f};

    for (int k0 = 0; k0 < 1024; k0 += 32) {
        __syncthreads();
        for (int j = tid; j < 512; j += 256) {
            int ar = j >> 3, kk = (j & 7) * 4;
            float4 v = *(const float4*)(A + (size_t)(r0 + ar) * 1024 + k0 + kk);
            A_l[ar][kk] = v.x; A_l[ar][kk + 1] = v.y;
            A_l[ar][kk + 2] = v.z; A_l[ar][kk + 3] = v.w;
        }
        if (tid < 128) {
            int wr = tid >> 3, kk = (tid & 7) * 4;
            float4 v = *(const float4*)(W + (size_t)(c0 + wr) * 1024 + k0 + kk);
            W_l[wr][kk] = v.x; W_l[wr][kk + 1] = v.y;
            W_l[wr][kk + 2] = v.z; W_l[wr][kk + 3] = v.w;
        }
        __syncthreads();
#pragma unroll
        for (int kk = 0; kk < 32; kk++) {
            float a = A_l[row][kk];
#pragma unroll
            for (int j = 0; j < 4; j++) acc[j] += a * W_l[cg * 4 + j][kk];
        }
    }
    const int r = r0 + row;
#pragma unroll
    for (int j = 0; j < 4; j++) {
        int c = c0 + cg * 4 + j;
        out[(size_t)r * 1024 + c] = acc[j] + bias[c];
    }
}

extern "C" void kernel_launch(void* const* d_in, const int* in_sizes, int n_in,
                              void* d_out, int out_size, void* d_ws, size_t ws_size,
                              hipStream_t stream) {
    const float* query = (const float*)d_in[0];
    // d_in[1] = key: unused by the reference (k_new/v_new project from query)
    const unsigned char* mask = (const unsigned char*)d_in[2];
    const float* kcache = (const float*)d_in[3];
    const float* vcache = (const float*)d_in[4];
    const float* Wq = (const float*)d_in[5];
    const float* bq = (const float*)d_in[6];
    const float* Wk = (const float*)d_in[7];
    const float* bk = (const float*)d_in[8];
    const float* Wv = (const float*)d_in[9];
    const float* bv = (const float*)d_in[10];
    const float* Wo = (const float*)d_in[11];
    const float* bo = (const float*)d_in[12];

    char* ws = (char*)d_ws;
    float* qs   = (float*)(ws);                       // 512 KB
    float* kn   = (float*)(ws + ( 512ull << 10));     // 512 KB
    float* vn   = (float*)(ws + (1024ull << 10));     // 512 KB
    float* att  = (float*)(ws + (1536ull << 10));     // 512 KB
    int*   flag = (int*)  (ws + (2048ull << 10));     // 4 B
    int*   cidx = (int*)  (ws + (2049ull << 10));     // 512 KB
    int*   ccnt = (int*)  (ws + (2562ull << 10));     // 128 B
    float* pml  = (float*)(ws + (2563ull << 10));     // 128 KB
    float* pacc = (float*)(ws + (3072ull << 10));     // 4 MB

    detect_mask<<<1, 256, 0, stream>>>(mask, flag);
    compact_kernel<<<B_, 256, 0, stream>>>(mask, flag, cidx, ccnt);
    proj_kernel<<<384, 256, 0, stream>>>(query, Wq, bq, Wk, bk, Wv, bv, qs, kn, vn);
    attn_kernel<<<512 * SPLIT_, 256, 0, stream>>>(kcache, vcache, qs, cidx, ccnt, pml, pacc);
    merge_kernel<<<512, 256, 0, stream>>>(pml, pacc, qs, kn, vn, mask, flag, att);
    oproj_kernel<<<128, 256, 0, stream>>>(att, Wo, bo, (float*)d_out);
}

// Round 6
// 290.820 us; speedup vs baseline: 1.0070x; 1.0029x over previous
//
#include <hip/hip_runtime.h>

typedef unsigned int u32;
typedef unsigned long long u64;

#define T_ 4
#define B_ 32
#define E_ 1024
#define H_ 16
#define HD_ 64
#define CACHE_ 4096
#define S_ 4100
#define SPLIT_ 2
#define NEGINF (-__builtin_inff())

// ---------------- mask dtype detection: 1 = bool bytes, 0 = int32 ----------------
__global__ void detect_mask(const unsigned char* __restrict__ m, int* __restrict__ flag) {
    __shared__ int cnt_s;
    if (threadIdx.x == 0) cnt_s = 0;
    __syncthreads();
    int cnt = 0;
    for (int i = threadIdx.x; i < 8192; i += 256) cnt += (m[i] != 0) ? 1 : 0;
#pragma unroll
    for (int off = 32; off; off >>= 1) cnt += __shfl_xor(cnt, off);
    if ((threadIdx.x & 63) == 0) atomicAdd(&cnt_s, cnt);
    __syncthreads();
    if (threadIdx.x == 0) *flag = (cnt_s > 2048) ? 1 : 0;
}

// ---------------- per-batch compaction of unmasked cache positions ----------------
__global__ __launch_bounds__(256) void compact_kernel(
    const unsigned char* __restrict__ mask8, const int* __restrict__ flag,
    int* __restrict__ cidx, int* __restrict__ ccnt)
{
    const int b = blockIdx.x;
    const int tid = threadIdx.x;
    const int w = tid >> 6, l = tid & 63;
    const int mode = *flag;
    const int* mask32 = (const int*)mask8;
    __shared__ int wcnt[4];
    __shared__ int base_s;
    if (tid == 0) base_s = 0;
    __syncthreads();
    for (int s0 = 0; s0 < CACHE_; s0 += 256) {
        int s = s0 + tid;
        bool ok = mode ? (mask8[(size_t)b * S_ + s] == 0) : (mask32[(size_t)b * S_ + s] == 0);
        u64 bal = __ballot(ok);
        int pre = (int)__popcll(bal & ((1ull << l) - 1));
        if (l == 0) wcnt[w] = (int)__popcll(bal);
        __syncthreads();
        int off = base_s;
#pragma unroll
        for (int i = 0; i < 4; i++) if (i < w) off += wcnt[i];
        if (ok) cidx[b * CACHE_ + off + pre] = s;
        __syncthreads();
        if (tid == 0) base_s += wcnt[0] + wcnt[1] + wcnt[2] + wcnt[3];
        __syncthreads();
    }
    if (tid == 0) ccnt[b] = base_s;
}

// ---------------- fused QKV projection (f32) ----------------
__global__ __launch_bounds__(256) void proj_kernel(
    const float* __restrict__ q,
    const float* __restrict__ Wq, const float* __restrict__ bq,
    const float* __restrict__ Wk, const float* __restrict__ bk,
    const float* __restrict__ Wv, const float* __restrict__ bv,
    float* __restrict__ qs, float* __restrict__ kn, float* __restrict__ vn)
{
    __shared__ float A_l[64][33];
    __shared__ float W_l[16][33];
    const int bx = blockIdx.x;
    const int mat = bx >> 7;
    const int rem = bx & 127;
    const int ct = rem >> 1, rt = rem & 1;
    const int c0 = ct * 16, r0 = rt * 64;
    const float* W    = (mat == 0) ? Wq : (mat == 1) ? Wk : Wv;
    const float* bias = (mat == 0) ? bq : (mat == 1) ? bk : bv;
    const int tid = threadIdx.x;
    const int row = tid & 63, cg = tid >> 6;
    float acc[4] = {0.f, 0.f, 0.f, 0.f};

    for (int k0 = 0; k0 < 1024; k0 += 32) {
        __syncthreads();
        for (int j = tid; j < 512; j += 256) {
            int ar = j >> 3, kk = (j & 7) * 4;
            float4 v = *(const float4*)(q + (size_t)(r0 + ar) * 1024 + k0 + kk);
            A_l[ar][kk] = v.x; A_l[ar][kk + 1] = v.y;
            A_l[ar][kk + 2] = v.z; A_l[ar][kk + 3] = v.w;
        }
        if (tid < 128) {
            int wr = tid >> 3, kk = (tid & 7) * 4;
            float4 v = *(const float4*)(W + (size_t)(c0 + wr) * 1024 + k0 + kk);
            W_l[wr][kk] = v.x; W_l[wr][kk + 1] = v.y;
            W_l[wr][kk + 2] = v.z; W_l[wr][kk + 3] = v.w;
        }
        __syncthreads();
#pragma unroll
        for (int kk = 0; kk < 32; kk++) {
            float a = A_l[row][kk];
#pragma unroll
            for (int j = 0; j < 4; j++) acc[j] += a * W_l[cg * 4 + j][kk];
        }
    }
    const int r = r0 + row;
    const int t = r >> 5, b = r & 31;
#pragma unroll
    for (int j = 0; j < 4; j++) {
        int c = c0 + cg * 4 + j;
        float val = acc[j] + bias[c];
        int h = c >> 6, d = c & 63;
        size_t oidx = ((size_t)((b * H_ + h) * T_ + t)) * HD_ + d;
        if (mat == 0) qs[oidx] = val * 0.125f;
        else if (mat == 1) kn[oidx] = val;
        else vn[oidx] = val;
    }
}

// ---------------- attention: barrier-free register-resident flash decode ----------------
// Grid: 512 * SPLIT_ blocks. Block (bh, split) processes compacted positions
// [lo, hi). Each wave owns disjoint rows; lane l = (group r4 = l>>2, quarter
// q4 = l&3) holds 16 floats of one K row and one V row in registers.
// Per-wave online softmax; partials (m, l, acc[4][64]) written for merge.
__global__ __launch_bounds__(256) void attn_kernel(
    const float* __restrict__ kcache, const float* __restrict__ vcache,
    const float* __restrict__ qs,
    const int* __restrict__ cidx, const int* __restrict__ ccnt,
    float* __restrict__ part_ml, float* __restrict__ part_acc)
{
    const int bid = blockIdx.x;
    const int bh = bid >> 1, split = bid & 1;
    const int b = bh >> 4;
    const int tid = threadIdx.x;
    const int w = tid >> 6, l = tid & 63;
    const int q4 = l & 3, r4 = l >> 2;

    __shared__ float q_l[256];
    __shared__ int cidx_l[2048];

    const int cnt = ccnt[b];
    const int half = (cnt + 1) >> 1;
    const int lo = split * half;
    const int hi = min(cnt, lo + half);
    const int n = hi - lo;

    q_l[tid] = qs[bh * 256 + tid];
    for (int i = tid; i < n; i += 256) cidx_l[i] = cidx[b * CACHE_ + lo + i];
    __syncthreads();

    float acc[4][16];
#pragma unroll
    for (int t = 0; t < 4; t++)
#pragma unroll
        for (int j = 0; j < 16; j++) acc[t][j] = 0.f;
    float m[4] = {NEGINF, NEGINF, NEGINF, NEGINF};
    float L[4] = {0.f, 0.f, 0.f, 0.f};

    // lane's 16 floats of a row: d = x*16 + q4*4 + {0..3}, x = 0..3
    // -> each dwordx4 instruction covers one full 64B line per 4-lane group.
    const float* kbase = kcache + (size_t)bh * (CACHE_ * HD_) + q4 * 4;
    const float* vbase = vcache + (size_t)bh * (CACHE_ * HD_) + q4 * 4;

    const int nch = (n + 63) >> 6;
    float4 ka[4], va[4];

    if (nch > 0) {
        int p = w * 16 + r4;
        int idx = cidx_l[min(p, n - 1)];
#pragma unroll
        for (int x = 0; x < 4; x++) ka[x] = *(const float4*)(kbase + (size_t)idx * HD_ + x * 16);
#pragma unroll
        for (int x = 0; x < 4; x++) va[x] = *(const float4*)(vbase + (size_t)idx * HD_ + x * 16);
    }

    for (int c = 0; c < nch; c++) {
        // ---- score partials from K registers ----
        float part[4] = {0.f, 0.f, 0.f, 0.f};
#pragma unroll
        for (int x = 0; x < 4; x++) {
            float4 kf = ka[x];
#pragma unroll
            for (int t = 0; t < 4; t++) {
                float4 qf = *(const float4*)&q_l[t * 64 + x * 16 + q4 * 4];
                part[t] += qf.x * kf.x + qf.y * kf.y + qf.z * kf.z + qf.w * kf.w;
            }
        }
        // ---- prefetch next-chunk K (ka registers now dead) ----
        if (c + 1 < nch) {
            int p = (c + 1) * 64 + w * 16 + r4;
            int idx = cidx_l[min(p, n - 1)];
#pragma unroll
            for (int x = 0; x < 4; x++) ka[x] = *(const float4*)(kbase + (size_t)idx * HD_ + x * 16);
        }
        const bool valid = (c * 64 + w * 16 + r4) < n;
        float pe[4];
#pragma unroll
        for (int t = 0; t < 4; t++) {
            float s = part[t];
            s += __shfl_xor(s, 1);
            s += __shfl_xor(s, 2);          // full dot, equal within 4-lane group
            s = valid ? s : NEGINF;
            float mx = s;
            mx = fmaxf(mx, __shfl_xor(mx, 4));
            mx = fmaxf(mx, __shfl_xor(mx, 8));
            mx = fmaxf(mx, __shfl_xor(mx, 16));
            mx = fmaxf(mx, __shfl_xor(mx, 32));   // wave max over 16 rows
            if (mx > m[t] + 8.f) {          // defer-max (T13): rare rescale
                float fac = __expf(m[t] - mx);
                L[t] *= fac;
#pragma unroll
                for (int j = 0; j < 16; j++) acc[t][j] *= fac;
                m[t] = mx;
            }
            float e = (s == NEGINF) ? 0.f : __expf(s - m[t]);
            float rs = e;
            rs += __shfl_xor(rs, 4);
            rs += __shfl_xor(rs, 8);
            rs += __shfl_xor(rs, 16);
            rs += __shfl_xor(rs, 32);       // sums 16 distinct rows exactly once
            L[t] += rs;
            pe[t] = e;
        }
        // ---- PV from V registers ----
#pragma unroll
        for (int t = 0; t < 4; t++) {
#pragma unroll
            for (int x = 0; x < 4; x++) {
                acc[t][x * 4 + 0] += pe[t] * va[x].x;
                acc[t][x * 4 + 1] += pe[t] * va[x].y;
                acc[t][x * 4 + 2] += pe[t] * va[x].z;
                acc[t][x * 4 + 3] += pe[t] * va[x].w;
            }
        }
        // ---- prefetch next-chunk V (va registers now dead) ----
        if (c + 1 < nch) {
            int p = (c + 1) * 64 + w * 16 + r4;
            int idx = cidx_l[min(p, n - 1)];
#pragma unroll
            for (int x = 0; x < 4; x++) va[x] = *(const float4*)(vbase + (size_t)idx * HD_ + x * 16);
        }
    }

    // reduce acc across the 16 row-groups of the wave
#pragma unroll
    for (int t = 0; t < 4; t++)
#pragma unroll
        for (int j = 0; j < 16; j++) {
            float v = acc[t][j];
            v += __shfl_xor(v, 4);
            v += __shfl_xor(v, 8);
            v += __shfl_xor(v, 16);
            v += __shfl_xor(v, 32);
            acc[t][j] = v;
        }

    const int pidx = bid * 4 + w;           // [0, 4096)
    if (l < 4) {                            // lanes 0..3: quarters 0..3
#pragma unroll
        for (int t = 0; t < 4; t++)
#pragma unroll
            for (int x = 0; x < 4; x++) {
                float4 o = make_float4(acc[t][x * 4], acc[t][x * 4 + 1],
                                       acc[t][x * 4 + 2], acc[t][x * 4 + 3]);
                *(float4*)&part_acc[((size_t)pidx * 4 + t) * HD_ + x * 16 + l * 4] = o;
            }
    }
    if (l == 0) {
#pragma unroll
        for (int t = 0; t < 4; t++) {
            part_ml[pidx * 8 + t * 2 + 0] = m[t];
            part_ml[pidx * 8 + t * 2 + 1] = L[t];
        }
    }
}

// ---------------- merge partials + new tokens + normalize ----------------
__global__ __launch_bounds__(256) void merge_kernel(
    const float* __restrict__ part_ml, const float* __restrict__ part_acc,
    const float* __restrict__ qs, const float* __restrict__ kn,
    const float* __restrict__ vn,
    const unsigned char* __restrict__ mask8, const int* __restrict__ flag,
    float* __restrict__ attn_out)
{
    const int bh = blockIdx.x;
    const int b = bh >> 4, h = bh & 15;
    const int tid = threadIdx.x;
    const int t = tid >> 6, d = tid & 63;
    const int mode = *flag;
    const int* mask32 = (const int*)mask8;

    float M = NEGINF;
#pragma unroll
    for (int i = 0; i < 8; i++) M = fmaxf(M, part_ml[(bh * 8 + i) * 8 + t * 2]);
    float acc = 0.f, L = 0.f;
#pragma unroll
    for (int i = 0; i < 8; i++) {
        float mi = part_ml[(bh * 8 + i) * 8 + t * 2];
        float li = part_ml[(bh * 8 + i) * 8 + t * 2 + 1];
        if (mi > NEGINF) {
            float wgt = __expf(mi - M);
            L += li * wgt;
            acc += part_acc[((size_t)(bh * 8 + i) * 4 + t) * HD_ + d] * wgt;
        }
    }

    // new-token keys (positions CACHE_..CACHE_+3)
    float qv = qs[bh * 256 + t * 64 + d];
    float sn[4];
#pragma unroll
    for (int i = 0; i < 4; i++) {
        size_t mi_ = (size_t)b * S_ + CACHE_ + i;
        bool masked = mode ? (mask8[mi_] != 0) : (mask32[mi_] != 0);
        float prod = qv * kn[bh * 256 + i * 64 + d];
        prod += __shfl_xor(prod, 1);
        prod += __shfl_xor(prod, 2);
        prod += __shfl_xor(prod, 4);
        prod += __shfl_xor(prod, 8);
        prod += __shfl_xor(prod, 16);
        prod += __shfl_xor(prod, 32);
        sn[i] = masked ? NEGINF : prod;
    }
    float M2 = M;
#pragma unroll
    for (int i = 0; i < 4; i++) M2 = fmaxf(M2, sn[i]);
    if (M2 > NEGINF) {
        if (M > NEGINF) {
            float wo = __expf(M - M2);
            acc *= wo; L *= wo;
        }
#pragma unroll
        for (int i = 0; i < 4; i++) {
            if (sn[i] > NEGINF) {
                float e = __expf(sn[i] - M2);
                L += e;
                acc += e * vn[bh * 256 + i * 64 + d];
            }
        }
    }
    float o = (L > 0.f) ? acc / L : 0.f;
    attn_out[(size_t)(t * B_ + b) * E_ + h * HD_ + d] = o;
}

// ---------------- output projection (f32 -> f32) ----------------
__global__ __launch_bounds__(256) void oproj_kernel(
    const float* __restrict__ A,
    const float* __restrict__ W, const float* __restrict__ bias,
    float* __restrict__ out)
{
    __shared__ float A_l[64][33];
    __shared__ float W_l[16][33];
    const int bx = blockIdx.x;
    const int ct = bx >> 1, rt = bx & 1;
    const int c0 = ct * 16, r0 = rt * 64;
    const int tid = threadIdx.x;
    const int row = tid & 63, cg = tid >> 6;
    float acc[4] = {0.f, 0.f, 0.f, 0.f};

    for (int k0 = 0; k0 < 1024; k0 += 32) {
        __syncthreads();
        for (int j = tid; j < 512; j += 256) {
            int ar = j >> 3, kk = (j & 7) * 4;
            float4 v = *(const float4*)(A + (size_t)(r0 + ar) * 1024 + k0 + kk);
            A_l[ar][kk] = v.x; A_l[ar][kk + 1] = v.y;
            A_l[ar][kk + 2] = v.z; A_l[ar][kk + 3] = v.w;
        }
        if (tid < 128) {
            int wr = tid >> 3, kk = (tid & 7) * 4;
            float4 v = *(const float4*)(W + (size_t)(c0 + wr) * 1024 + k0 + kk);
            W_l[wr][kk] = v.x; W_l[wr][kk + 1] = v.y;
            W_l[wr][kk + 2] = v.z; W_l[wr][kk + 3] = v.w;
        }
        __syncthreads();
#pragma unroll
        for (int kk = 0; kk < 32; kk++) {
            float a = A_l[row][kk];
#pragma unroll
            for (int j = 0; j < 4; j++) acc[j] += a * W_l[cg * 4 + j][kk];
        }
    }
    const int r = r0 + row;
#pragma unroll
    for (int j = 0; j < 4; j++) {
        int c = c0 + cg * 4 + j;
        out[(size_t)r * 1024 + c] = acc[j] + bias[c];
    }
}

extern "C" void kernel_launch(void* const* d_in, const int* in_sizes, int n_in,
                              void* d_out, int out_size, void* d_ws, size_t ws_size,
                              hipStream_t stream) {
    const float* query = (const float*)d_in[0];
    // d_in[1] = key: unused by the reference (k_new/v_new project from query)
    const unsigned char* mask = (const unsigned char*)d_in[2];
    const float* kcache = (const float*)d_in[3];
    const float* vcache = (const float*)d_in[4];
    const float* Wq = (const float*)d_in[5];
    const float* bq = (const float*)d_in[6];
    const float* Wk = (const float*)d_in[7];
    const float* bk = (const float*)d_in[8];
    const float* Wv = (const float*)d_in[9];
    const float* bv = (const float*)d_in[10];
    const float* Wo = (const float*)d_in[11];
    const float* bo = (const float*)d_in[12];

    char* ws = (char*)d_ws;
    float* qs   = (float*)(ws);                       // 512 KB
    float* kn   = (float*)(ws + ( 512ull << 10));     // 512 KB
    float* vn   = (float*)(ws + (1024ull << 10));     // 512 KB
    float* att  = (float*)(ws + (1536ull << 10));     // 512 KB
    int*   flag = (int*)  (ws + (2048ull << 10));     // 4 B
    int*   cidx = (int*)  (ws + (2049ull << 10));     // 512 KB
    int*   ccnt = (int*)  (ws + (2562ull << 10));     // 128 B
    float* pml  = (float*)(ws + (2563ull << 10));     // 128 KB
    float* pacc = (float*)(ws + (3072ull << 10));     // 4 MB

    detect_mask<<<1, 256, 0, stream>>>(mask, flag);
    compact_kernel<<<B_, 256, 0, stream>>>(mask, flag, cidx, ccnt);
    proj_kernel<<<384, 256, 0, stream>>>(query, Wq, bq, Wk, bk, Wv, bv, qs, kn, vn);
    attn_kernel<<<512 * SPLIT_, 256, 0, stream>>>(kcache, vcache, qs, cidx, ccnt, pml, pacc);
    merge_kernel<<<512, 256, 0, stream>>>(pml, pacc, qs, kn, vn, mask, flag, att);
    oproj_kernel<<<128, 256, 0, stream>>>(att, Wo, bo, (float*)d_out);
}

// Round 7
// 280.797 us; speedup vs baseline: 1.0429x; 1.0357x over previous
//
#include <hip/hip_runtime.h>

typedef unsigned int u32;
typedef unsigned long long u64;

#define T_ 4
#define B_ 32
#define E_ 1024
#define H_ 16
#define HD_ 64
#define CACHE_ 4096
#define S_ 4100
#define SPLIT_ 2
#define NEGINF (-__builtin_inff())

// ---------------- mask dtype detection: 1 = bool bytes, 0 = int32 ----------------
__global__ void detect_mask(const unsigned char* __restrict__ m, int* __restrict__ flag) {
    __shared__ int cnt_s;
    if (threadIdx.x == 0) cnt_s = 0;
    __syncthreads();
    int cnt = 0;
    for (int i = threadIdx.x; i < 8192; i += 256) cnt += (m[i] != 0) ? 1 : 0;
#pragma unroll
    for (int off = 32; off; off >>= 1) cnt += __shfl_xor(cnt, off);
    if ((threadIdx.x & 63) == 0) atomicAdd(&cnt_s, cnt);
    __syncthreads();
    if (threadIdx.x == 0) *flag = (cnt_s > 2048) ? 1 : 0;
}

// ---------------- per-batch compaction of unmasked cache positions ----------------
__global__ __launch_bounds__(1024) void compact_kernel(
    const unsigned char* __restrict__ mask8, const int* __restrict__ flag,
    int* __restrict__ cidx, int* __restrict__ ccnt)
{
    const int b = blockIdx.x;
    const int tid = threadIdx.x;
    const int w = tid >> 6, l = tid & 63;
    const int mode = *flag;
    const int* mask32 = (const int*)mask8;
    __shared__ int wcnt[16];
    __shared__ int base_s;
    if (tid == 0) base_s = 0;
    __syncthreads();
    for (int s0 = 0; s0 < CACHE_; s0 += 1024) {
        int s = s0 + tid;
        bool ok = mode ? (mask8[(size_t)b * S_ + s] == 0) : (mask32[(size_t)b * S_ + s] == 0);
        u64 bal = __ballot(ok);
        int pre = (int)__popcll(bal & ((1ull << l) - 1));
        if (l == 0) wcnt[w] = (int)__popcll(bal);
        __syncthreads();
        int off = base_s;
#pragma unroll
        for (int i = 0; i < 16; i++) if (i < w) off += wcnt[i];
        if (ok) cidx[b * CACHE_ + off + pre] = s;
        __syncthreads();
        if (tid == 0) {
            int tot = 0;
#pragma unroll
            for (int i = 0; i < 16; i++) tot += wcnt[i];
            base_s += tot;
        }
        __syncthreads();
    }
    if (tid == 0) ccnt[b] = base_s;
}

// ---------------- fused QKV projection (f32) ----------------
__global__ __launch_bounds__(256) void proj_kernel(
    const float* __restrict__ q,
    const float* __restrict__ Wq, const float* __restrict__ bq,
    const float* __restrict__ Wk, const float* __restrict__ bk,
    const float* __restrict__ Wv, const float* __restrict__ bv,
    float* __restrict__ qs, float* __restrict__ kn, float* __restrict__ vn)
{
    __shared__ float A_l[64][33];
    __shared__ float W_l[16][33];
    const int bx = blockIdx.x;
    const int mat = bx >> 7;
    const int rem = bx & 127;
    const int ct = rem >> 1, rt = rem & 1;
    const int c0 = ct * 16, r0 = rt * 64;
    const float* W    = (mat == 0) ? Wq : (mat == 1) ? Wk : Wv;
    const float* bias = (mat == 0) ? bq : (mat == 1) ? bk : bv;
    const int tid = threadIdx.x;
    const int row = tid & 63, cg = tid >> 6;
    float acc[4] = {0.f, 0.f, 0.f, 0.f};

    for (int k0 = 0; k0 < 1024; k0 += 32) {
        __syncthreads();
        for (int j = tid; j < 512; j += 256) {
            int ar = j >> 3, kk = (j & 7) * 4;
            float4 v = *(const float4*)(q + (size_t)(r0 + ar) * 1024 + k0 + kk);
            A_l[ar][kk] = v.x; A_l[ar][kk + 1] = v.y;
            A_l[ar][kk + 2] = v.z; A_l[ar][kk + 3] = v.w;
        }
        if (tid < 128) {
            int wr = tid >> 3, kk = (tid & 7) * 4;
            float4 v = *(const float4*)(W + (size_t)(c0 + wr) * 1024 + k0 + kk);
            W_l[wr][kk] = v.x; W_l[wr][kk + 1] = v.y;
            W_l[wr][kk + 2] = v.z; W_l[wr][kk + 3] = v.w;
        }
        __syncthreads();
#pragma unroll
        for (int kk = 0; kk < 32; kk++) {
            float a = A_l[row][kk];
#pragma unroll
            for (int j = 0; j < 4; j++) acc[j] += a * W_l[cg * 4 + j][kk];
        }
    }
    const int r = r0 + row;
    const int t = r >> 5, b = r & 31;
#pragma unroll
    for (int j = 0; j < 4; j++) {
        int c = c0 + cg * 4 + j;
        float val = acc[j] + bias[c];
        int h = c >> 6, d = c & 63;
        size_t oidx = ((size_t)((b * H_ + h) * T_ + t)) * HD_ + d;
        if (mat == 0) qs[oidx] = val * 0.125f;
        else if (mat == 1) kn[oidx] = val;
        else vn[oidx] = val;
    }
}

// ---------------- attention: 128B-transaction, lane-local-softmax flash decode ----------------
// Lane (r8 = l>>3, sub = l&7): row r8 of each 8-row chunk; dims {sub*4..+3} and
// {32+sub*4..+3} (8 lanes x 16B = one 128B transaction per row per instr).
// Online softmax (m, L) kept LANE-LOCAL (per lane's own rows); single cross-r8
// merge at kernel end. K/V double-buffered in registers (A/B sets).
__global__ __launch_bounds__(256, 4) void attn_kernel(
    const float* __restrict__ kcache, const float* __restrict__ vcache,
    const float* __restrict__ qs,
    const int* __restrict__ cidx, const int* __restrict__ ccnt,
    float* __restrict__ part_ml, float* __restrict__ part_acc)
{
    const int bid = blockIdx.x;
    const int bh = bid >> 1, split = bid & 1;
    const int b = bh >> 4;
    const int tid = threadIdx.x;
    const int w = tid >> 6, l = tid & 63;
    const int sub = l & 7, r8 = l >> 3;

    __shared__ float q_l[256];
    __shared__ int cidx_l[2048];

    const int cnt = ccnt[b];
    const int half = (cnt + 1) >> 1;
    const int lo = split * half;
    const int hi = min(cnt, lo + half);
    const int n = hi - lo;

    q_l[tid] = qs[bh * 256 + tid];
    for (int i = tid; i < n; i += 256) cidx_l[i] = cidx[b * CACHE_ + lo + i];
    __syncthreads();

    // hoisted q: per t, dims {sub*4..+3} (qa) and {32+sub*4..+3} (qb)
    float4 qa[4], qb[4];
#pragma unroll
    for (int t = 0; t < 4; t++) {
        qa[t] = *(const float4*)&q_l[t * 64 + sub * 4];
        qb[t] = *(const float4*)&q_l[t * 64 + 32 + sub * 4];
    }

    float4 o0[4], o1[4];
#pragma unroll
    for (int t = 0; t < 4; t++) {
        o0[t] = make_float4(0.f, 0.f, 0.f, 0.f);
        o1[t] = make_float4(0.f, 0.f, 0.f, 0.f);
    }
    float m[4] = {NEGINF, NEGINF, NEGINF, NEGINF};
    float L[4] = {0.f, 0.f, 0.f, 0.f};

    const float* kb = kcache + (size_t)bh * (CACHE_ * HD_) + sub * 4;
    const float* vb = vcache + (size_t)bh * (CACHE_ * HD_) + sub * 4;

    const int nch = (n + 31) >> 5;        // 32 rows per block-chunk (8 per wave)
    const int pbase = w * 8 + r8;

    float4 kA0, kA1, vA0, vA1, kB0, kB1, vB0, vB1;

#define ISSUE(K0, K1, V0, V1, CC) {                                   \
        int idx_ = cidx_l[min(pbase + (CC) * 32, n - 1)];             \
        const float* kp_ = kb + ((size_t)idx_ << 6);                  \
        const float* vp_ = vb + ((size_t)idx_ << 6);                  \
        K0 = *(const float4*)kp_;  K1 = *(const float4*)(kp_ + 32);   \
        V0 = *(const float4*)vp_;  V1 = *(const float4*)(vp_ + 32);   \
    }

#define PROCESS(K0, K1, V0, V1, CC) {                                               \
        const bool valid_ = ((CC) * 32 + pbase) < n;                                \
        _Pragma("unroll")                                                           \
        for (int t = 0; t < 4; t++) {                                               \
            float part = qa[t].x * K0.x + qa[t].y * K0.y + qa[t].z * K0.z           \
                       + qa[t].w * K0.w + qb[t].x * K1.x + qb[t].y * K1.y           \
                       + qb[t].z * K1.z + qb[t].w * K1.w;                           \
            part += __shfl_xor(part, 1);                                            \
            part += __shfl_xor(part, 2);                                            \
            part += __shfl_xor(part, 4);                                            \
            float s = valid_ ? part : NEGINF;                                       \
            if (s > m[t] + 8.f) {       /* defer-max: rare rescale */               \
                float fac = __expf(m[t] - s);                                       \
                L[t] *= fac;                                                        \
                o0[t].x *= fac; o0[t].y *= fac; o0[t].z *= fac; o0[t].w *= fac;     \
                o1[t].x *= fac; o1[t].y *= fac; o1[t].z *= fac; o1[t].w *= fac;     \
                m[t] = s;                                                           \
            }                                                                       \
            float e = (s == NEGINF) ? 0.f : __expf(s - m[t]);                       \
            L[t] += e;                                                              \
            o0[t].x += e * V0.x; o0[t].y += e * V0.y;                               \
            o0[t].z += e * V0.z; o0[t].w += e * V0.w;                               \
            o1[t].x += e * V1.x; o1[t].y += e * V1.y;                               \
            o1[t].z += e * V1.z; o1[t].w += e * V1.w;                               \
        }                                                                           \
    }

    if (nch > 0) ISSUE(kA0, kA1, vA0, vA1, 0);
    if (nch > 1) ISSUE(kB0, kB1, vB0, vB1, 1);

    for (int c = 0; c < nch; c += 2) {
        PROCESS(kA0, kA1, vA0, vA1, c);
        if (c + 2 < nch) ISSUE(kA0, kA1, vA0, vA1, c + 2);
        if (c + 1 < nch) {
            PROCESS(kB0, kB1, vB0, vB1, c + 1);
            if (c + 3 < nch) ISSUE(kB0, kB1, vB0, vB1, c + 3);
        }
    }
#undef ISSUE
#undef PROCESS

    // ---- end merge across the 8 r8-groups (lanes differ in bits 3,4,5) ----
    const int pidx = bid * 4 + w;           // [0, 4096)
#pragma unroll
    for (int t = 0; t < 4; t++) {
        float M = m[t];
        M = fmaxf(M, __shfl_xor(M, 8));
        M = fmaxf(M, __shfl_xor(M, 16));
        M = fmaxf(M, __shfl_xor(M, 32));
        float fac = (m[t] == NEGINF) ? 0.f : __expf(m[t] - M);
        float Lr = L[t] * fac;
        Lr += __shfl_xor(Lr, 8);
        Lr += __shfl_xor(Lr, 16);
        Lr += __shfl_xor(Lr, 32);
        float a0x = o0[t].x * fac, a0y = o0[t].y * fac,
              a0z = o0[t].z * fac, a0w = o0[t].w * fac;
        float a1x = o1[t].x * fac, a1y = o1[t].y * fac,
              a1z = o1[t].z * fac, a1w = o1[t].w * fac;
#pragma unroll
        for (int off = 8; off <= 32; off <<= 1) {
            a0x += __shfl_xor(a0x, off); a0y += __shfl_xor(a0y, off);
            a0z += __shfl_xor(a0z, off); a0w += __shfl_xor(a0w, off);
            a1x += __shfl_xor(a1x, off); a1y += __shfl_xor(a1y, off);
            a1z += __shfl_xor(a1z, off); a1w += __shfl_xor(a1w, off);
        }
        if (r8 == 0) {
            *(float4*)&part_acc[((size_t)pidx * 4 + t) * HD_ + sub * 4] =
                make_float4(a0x, a0y, a0z, a0w);
            *(float4*)&part_acc[((size_t)pidx * 4 + t) * HD_ + 32 + sub * 4] =
                make_float4(a1x, a1y, a1z, a1w);
        }
        if (l == 0) {
            part_ml[pidx * 8 + t * 2 + 0] = M;
            part_ml[pidx * 8 + t * 2 + 1] = Lr;
        }
    }
}

// ---------------- merge partials + new tokens + normalize ----------------
__global__ __launch_bounds__(256) void merge_kernel(
    const float* __restrict__ part_ml, const float* __restrict__ part_acc,
    const float* __restrict__ qs, const float* __restrict__ kn,
    const float* __restrict__ vn,
    const unsigned char* __restrict__ mask8, const int* __restrict__ flag,
    float* __restrict__ attn_out)
{
    const int bh = blockIdx.x;
    const int b = bh >> 4, h = bh & 15;
    const int tid = threadIdx.x;
    const int t = tid >> 6, d = tid & 63;
    const int mode = *flag;
    const int* mask32 = (const int*)mask8;

    float M = NEGINF;
#pragma unroll
    for (int i = 0; i < 8; i++) M = fmaxf(M, part_ml[(bh * 8 + i) * 8 + t * 2]);
    float acc = 0.f, L = 0.f;
#pragma unroll
    for (int i = 0; i < 8; i++) {
        float mi = part_ml[(bh * 8 + i) * 8 + t * 2];
        float li = part_ml[(bh * 8 + i) * 8 + t * 2 + 1];
        if (mi > NEGINF) {
            float wgt = __expf(mi - M);
            L += li * wgt;
            acc += part_acc[((size_t)(bh * 8 + i) * 4 + t) * HD_ + d] * wgt;
        }
    }

    // new-token keys (positions CACHE_..CACHE_+3)
    float qv = qs[bh * 256 + t * 64 + d];
    float sn[4];
#pragma unroll
    for (int i = 0; i < 4; i++) {
        size_t mi_ = (size_t)b * S_ + CACHE_ + i;
        bool masked = mode ? (mask8[mi_] != 0) : (mask32[mi_] != 0);
        float prod = qv * kn[bh * 256 + i * 64 + d];
        prod += __shfl_xor(prod, 1);
        prod += __shfl_xor(prod, 2);
        prod += __shfl_xor(prod, 4);
        prod += __shfl_xor(prod, 8);
        prod += __shfl_xor(prod, 16);
        prod += __shfl_xor(prod, 32);
        sn[i] = masked ? NEGINF : prod;
    }
    float M2 = M;
#pragma unroll
    for (int i = 0; i < 4; i++) M2 = fmaxf(M2, sn[i]);
    if (M2 > NEGINF) {
        if (M > NEGINF) {
            float wo = __expf(M - M2);
            acc *= wo; L *= wo;
        }
#pragma unroll
        for (int i = 0; i < 4; i++) {
            if (sn[i] > NEGINF) {
                float e = __expf(sn[i] - M2);
                L += e;
                acc += e * vn[bh * 256 + i * 64 + d];
            }
        }
    }
    float o = (L > 0.f) ? acc / L : 0.f;
    attn_out[(size_t)(t * B_ + b) * E_ + h * HD_ + d] = o;
}

// ---------------- output projection (f32 -> f32) ----------------
__global__ __launch_bounds__(256) void oproj_kernel(
    const float* __restrict__ A,
    const float* __restrict__ W, const float* __restrict__ bias,
    float* __restrict__ out)
{
    __shared__ float A_l[64][33];
    __shared__ float W_l[16][33];
    const int bx = blockIdx.x;
    const int ct = bx >> 1, rt = bx & 1;
    const int c0 = ct * 16, r0 = rt * 64;
    const int tid = threadIdx.x;
    const int row = tid & 63, cg = tid >> 6;
    float acc[4] = {0.f, 0.f, 0.f, 0.f};

    for (int k0 = 0; k0 < 1024; k0 += 32) {
        __syncthreads();
        for (int j = tid; j < 512; j += 256) {
            int ar = j >> 3, kk = (j & 7) * 4;
            float4 v = *(const float4*)(A + (size_t)(r0 + ar) * 1024 + k0 + kk);
            A_l[ar][kk] = v.x; A_l[ar][kk + 1] = v.y;
            A_l[ar][kk + 2] = v.z; A_l[ar][kk + 3] = v.w;
        }
        if (tid < 128) {
            int wr = tid >> 3, kk = (tid & 7) * 4;
            float4 v = *(const float4*)(W + (size_t)(c0 + wr) * 1024 + k0 + kk);
            W_l[wr][kk] = v.x; W_l[wr][kk + 1] = v.y;
            W_l[wr][kk + 2] = v.z; W_l[wr][kk + 3] = v.w;
        }
        __syncthreads();
#pragma unroll
        for (int kk = 0; kk < 32; kk++) {
            float a = A_l[row][kk];
#pragma unroll
            for (int j = 0; j < 4; j++) acc[j] += a * W_l[cg * 4 + j][kk];
        }
    }
    const int r = r0 + row;
#pragma unroll
    for (int j = 0; j < 4; j++) {
        int c = c0 + cg * 4 + j;
        out[(size_t)r * 1024 + c] = acc[j] + bias[c];
    }
}

extern "C" void kernel_launch(void* const* d_in, const int* in_sizes, int n_in,
                              void* d_out, int out_size, void* d_ws, size_t ws_size,
                              hipStream_t stream) {
    const float* query = (const float*)d_in[0];
    // d_in[1] = key: unused by the reference (k_new/v_new project from query)
    const unsigned char* mask = (const unsigned char*)d_in[2];
    const float* kcache = (const float*)d_in[3];
    const float* vcache = (const float*)d_in[4];
    const float* Wq = (const float*)d_in[5];
    const float* bq = (const float*)d_in[6];
    const float* Wk = (const float*)d_in[7];
    const float* bk = (const float*)d_in[8];
    const float* Wv = (const float*)d_in[9];
    const float* bv = (const float*)d_in[10];
    const float* Wo = (const float*)d_in[11];
    const float* bo = (const float*)d_in[12];

    char* ws = (char*)d_ws;
    float* qs   = (float*)(ws);                       // 512 KB
    float* kn   = (float*)(ws + ( 512ull << 10));     // 512 KB
    float* vn   = (float*)(ws + (1024ull << 10));     // 512 KB
    float* att  = (float*)(ws + (1536ull << 10));     // 512 KB
    int*   flag = (int*)  (ws + (2048ull << 10));     // 4 B
    int*   cidx = (int*)  (ws + (2049ull << 10));     // 512 KB
    int*   ccnt = (int*)  (ws + (2562ull << 10));     // 128 B
    float* pml  = (float*)(ws + (2563ull << 10));     // 128 KB
    float* pacc = (float*)(ws + (3072ull << 10));     // 4 MB

    detect_mask<<<1, 256, 0, stream>>>(mask, flag);
    compact_kernel<<<B_, 1024, 0, stream>>>(mask, flag, cidx, ccnt);
    proj_kernel<<<384, 256, 0, stream>>>(query, Wq, bq, Wk, bk, Wv, bv, qs, kn, vn);
    attn_kernel<<<512 * SPLIT_, 256, 0, stream>>>(kcache, vcache, qs, cidx, ccnt, pml, pacc);
    merge_kernel<<<512, 256, 0, stream>>>(pml, pacc, qs, kn, vn, mask, flag, att);
    oproj_kernel<<<128, 256, 0, stream>>>(att, Wo, bo, (float*)d_out);
}